// Round 10
// baseline (219.125 us; speedup 1.0000x reference)
//
#include <hip/hip_runtime.h>
#include <hip/hip_bf16.h>
#include <math.h>

#define N_PTS 8192
#define S_PTS 4096
typedef unsigned long long u64;
typedef unsigned u32;

// Strict fp32 gram-formula d^2 (bit-identical to the reference cdist pipeline).
__device__ __forceinline__ float d2_f32_gram(const float4 a, const float4 b) {
    float dot = __fadd_rn(__fadd_rn(__fmul_rn(a.x, b.x), __fmul_rn(a.y, b.y)),
                          __fmul_rn(a.z, b.z));
    float d2 = __fsub_rn(__fadd_rn(a.w, b.w), __fmul_rn(2.0f, dot));
    return fmaxf(d2, 0.0f);
}

// Reference-exact pair distance: fp32 gram + fp32 sqrt (== cdist output bits).
__device__ __forceinline__ float pair_dist_f(const float4 a, const float4 b) {
    float d2 = d2_f32_gram(a, b);
    return d2 > 0.0f ? __fsqrt_rn(d2) : 0.0f;
}

// ---------------------------------------------------------------- stage
__global__ __launch_bounds__(256) void stage_kernel(
        const float* __restrict__ xyz, const int* __restrict__ sidx,
        float4* __restrict__ cb, float4* __restrict__ ca,
        float* __restrict__ out_xyz_s) {
    int i = blockIdx.x * blockDim.x + threadIdx.x;
    if (i < N_PTS) {
        float x = xyz[i * 3 + 0], y = xyz[i * 3 + 1], z = xyz[i * 3 + 2];
        float sq = __fadd_rn(__fadd_rn(__fmul_rn(x, x), __fmul_rn(y, y)),
                             __fmul_rn(z, z));
        cb[i] = make_float4(x, y, z, sq);
    }
    if (i < S_PTS) {
        int si = sidx[i];
        float x = xyz[si * 3 + 0], y = xyz[si * 3 + 1], z = xyz[si * 3 + 2];
        float sq = __fadd_rn(__fadd_rn(__fmul_rn(x, x), __fmul_rn(y, y)),
                             __fmul_rn(z, z));
        ca[i] = make_float4(x, y, z, sq);
        out_xyz_s[i * 3 + 0] = x;
        out_xyz_s[i * 3 + 1] = y;
        out_xyz_s[i * 3 + 2] = z;
    }
}

// ---------------------------------------------------------------- knn select
// Validated r1/r4/r6 structure: Q queries per block share each candidate load;
// wave w owns query w for tau-sort / final-sort / epilogue.
// r10 change: __launch_bounds__(256, 8) — compiler already allocates exactly
// 64 VGPR (the 8-waves/EU budget), so declare it and double target residency
// for this latency-bound kernel (occupancy was 38%).

// full single-wave ladder (ultra-rare fallback), per owning wave
template <int KOUT, int ITERS>
__device__ u64 knn_full_ladder(const float4 q, const float4* __restrict__ cand,
                               int lane) {
    u32 Lk[KOUT], Li[KOUT];
#pragma unroll
    for (int j = 0; j < KOUT; ++j) { Lk[j] = 0xFFFFFFFFu; Li[j] = 0xFFFFFFFFu; }
    int c = lane;
    for (int tt = 0; tt < ITERS; ++tt, c += 64) {
        float d2 = d2_f32_gram(q, cand[c]);
        float Df = d2 > 0.0f ? __fsqrt_rn(d2) : 0.0f;
        u32 kb = __float_as_uint(Df);
        if (kb < Lk[KOUT - 1]) {
#pragma unroll
            for (int j = KOUT - 1; j >= 1; --j) {
                bool up = kb < Lk[j - 1], ins = kb < Lk[j];
                Lk[j] = up ? Lk[j - 1] : (ins ? kb : Lk[j]);
                Li[j] = up ? Li[j - 1] : (ins ? (u32)c : Li[j]);
            }
            bool i0 = kb < Lk[0];
            Lk[0] = i0 ? kb : Lk[0];
            Li[0] = i0 ? (u32)c : Li[0];
        }
    }
    u64 Lu[KOUT];
#pragma unroll
    for (int j = 0; j < KOUT; ++j) Lu[j] = ((u64)Lk[j] << 32) | (u64)Li[j];
    u64 res = ~0ull;
#pragma unroll
    for (int r = 0; r < KOUT; ++r) {
        u64 m = Lu[0];
#pragma unroll
        for (int off = 32; off >= 1; off >>= 1) {
            u64 o = __shfl_xor(m, off, 64);
            m = (o < m) ? o : m;
        }
        if (lane == r) res = m;
        if (Lu[0] == m) {
#pragma unroll
            for (int j = 0; j < KOUT - 1; ++j) Lu[j] = Lu[j + 1];
            Lu[KOUT - 1] = ~0ull;
        }
    }
    return res;
}

// Sort the compacted candidate buffer of one query (executed by its owning
// wave only).
template <int K, int NC>
__device__ u64 final_select(const float4 qq, const float4* __restrict__ cand,
                            const u64* bufq, u32 cnt, int lane) {
    if (cnt <= 64u) {
        u64 v = (lane < (int)cnt) ? bufq[lane] : ~0ull;
#pragma unroll
        for (int k = 2; k <= 64; k <<= 1) {
#pragma unroll
            for (int j2 = k >> 1; j2 >= 1; j2 >>= 1) {
                u64 o = __shfl_xor(v, j2, 64);
                bool keepMin = (((lane & j2) == 0) == ((lane & k) == 0));
                bool less = o < v;
                v = keepMin ? (less ? o : v) : (less ? v : o);
            }
        }
        return v;  // lane r holds rank r
    } else if (cnt <= 256u) {
        // per-lane sorted-4 (<=4 cands/lane) + K-round extract
        u64 L0 = ~0ull, L1 = ~0ull, L2 = ~0ull, L3 = ~0ull;
        for (u32 mm = lane; mm < cnt; mm += 64) {
            u64 kk = bufq[mm];
            if (kk < L3) {
                if (kk < L1) {
                    L3 = L2; L2 = L1;
                    if (kk < L0) { L1 = L0; L0 = kk; } else L1 = kk;
                } else {
                    if (kk < L2) { L3 = L2; L2 = kk; } else L3 = kk;
                }
            }
        }
        u64 res = ~0ull;
#pragma unroll
        for (int r = 0; r < K; ++r) {
            u64 mr = L0;
#pragma unroll
            for (int off = 32; off >= 1; off >>= 1) {
                u64 o = __shfl_xor(mr, off, 64);
                mr = (o < mr) ? o : mr;
            }
            if (lane == r) res = mr;
            if (L0 == mr) { L0 = L1; L1 = L2; L2 = L3; L3 = ~0ull; }
        }
        return res;
    }
    return knn_full_ladder<K, NC / 64>(qq, cand, lane);
}

// Q-query batched select. mins: Q*256 u32, buf: Q*256 u64, shm: >= Q + 4*Q u32.
// Returns the (D,idx) record for rank `lane` of query `wid` (valid iff wid<Q).
template <int J, int K, int NC, int Q>
__device__ __forceinline__ u64 knn_selectq(
        const float4* qs, const float4* __restrict__ cand, int t,
        u32* mins, u64* buf, u32* shm) {
    int lane = t & 63, wid = t >> 6;
    // pass 1: d^2 bits in registers + per-thread min, Q queries per load
    u32 d2b[Q][J];
    u32 m[Q];
#pragma unroll
    for (int qi = 0; qi < Q; ++qi) m[qi] = 0xFFFFFFFFu;
#pragma unroll
    for (int j = 0; j < J; ++j) {
        float4 c = cand[t + 256 * j];
#pragma unroll
        for (int qi = 0; qi < Q; ++qi) {
            u32 b = __float_as_uint(d2_f32_gram(qs[qi], c));
            d2b[qi][j] = b;
            m[qi] = b < m[qi] ? b : m[qi];
        }
    }
#pragma unroll
    for (int qi = 0; qi < Q; ++qi) mins[qi * 256 + t] = m[qi];
    __syncthreads();
    // tau[qi] = K-th smallest of 64 column-minima (wave qi, bitonic sort64 u32)
    if (wid < Q) {
        const u32* mq = mins + wid * 256;
        u32 v = mq[lane];
        u32 v2 = mq[lane + 64];  v = v2 < v ? v2 : v;
        v2 = mq[lane + 128];     v = v2 < v ? v2 : v;
        v2 = mq[lane + 192];     v = v2 < v ? v2 : v;
#pragma unroll
        for (int k = 2; k <= 64; k <<= 1) {
#pragma unroll
            for (int j2 = k >> 1; j2 >= 1; j2 >>= 1) {
                u32 o = __shfl_xor(v, j2, 64);
                bool keepMin = (((lane & j2) == 0) == ((lane & k) == 0));
                bool less = o < v;
                v = keepMin ? (less ? o : v) : (less ? v : o);
            }
        }
        if (lane == K - 1) shm[wid] = v;
    }
    __syncthreads();
    // pass 2: count qualifying + block prefix scan, per query
    u32 tau[Q], c[Q], x[Q];
#pragma unroll
    for (int qi = 0; qi < Q; ++qi) {
        tau[qi] = shm[qi];
        u32 cc = 0;
#pragma unroll
        for (int j = 0; j < J; ++j) cc += (d2b[qi][j] <= tau[qi]) ? 1u : 0u;
        c[qi] = cc;
        u32 xx = cc;
#pragma unroll
        for (int off = 1; off < 64; off <<= 1) {
            u32 y = __shfl_up(xx, off, 64);
            if (lane >= off) xx += y;
        }
        x[qi] = xx;
        if (lane == 63) shm[Q + qi * 4 + wid] = xx;
    }
    __syncthreads();
    u32 cnt[Q];
#pragma unroll
    for (int qi = 0; qi < Q; ++qi) {
        u32 base = x[qi] - c[qi];
        for (int w = 0; w < wid; ++w) base += shm[Q + qi * 4 + w];
        cnt[qi] = shm[Q + qi * 4 + 0] + shm[Q + qi * 4 + 1] +
                  shm[Q + qi * 4 + 2] + shm[Q + qi * 4 + 3];
        if (cnt[qi] <= 256u) {
            u32 off = base;
#pragma unroll
            for (int j = 0; j < J; ++j) {
                if (d2b[qi][j] <= tau[qi]) {
                    float d2 = __uint_as_float(d2b[qi][j]);
                    float D = d2 > 0.0f ? __fsqrt_rn(d2) : 0.0f;
                    buf[qi * 256 + off++] = ((u64)__float_as_uint(D) << 32) |
                                            (u64)(u32)(t + 256 * j);
                }
            }
        }
    }
    __syncthreads();
    u64 res = ~0ull;
#pragma unroll
    for (int qi = 0; qi < Q; ++qi)
        if (wid == qi)
            res = final_select<K, NC>(qs[qi], cand, buf + qi * 256, cnt[qi], lane);
    return res;
}

// blocks [0, 1024): "after" (top-16 over ca, 4 queries/block);
// blocks [1024, 3072): "before" (top-4 over cb, 2 queries/block)
__global__ __launch_bounds__(256, 8) void knn_kernel(
        const float4* __restrict__ cb, const float4* __restrict__ ca,
        const int* __restrict__ sidx,
        int* __restrict__ a_before, float* __restrict__ intra_before,
        int* __restrict__ ni_i, float* __restrict__ intra_after,
        float* __restrict__ out_ni) {
    __shared__ u32 mins[4 * 256];
    __shared__ u64 buf[4 * 256];
    __shared__ u32 shm[24];
    int t = threadIdx.x, lane = t & 63, wid = t >> 6;
    int bid = blockIdx.x;
    if (bid < S_PTS / 4) {
        int s0 = bid * 4;
        float4 qs[4];
#pragma unroll
        for (int qi = 0; qi < 4; ++qi) qs[qi] = ca[s0 + qi];
        u64 res = knn_selectq<16, 16, 4096, 4>(qs, ca, t, mins, buf, shm);
        if (wid < 4) {
            int s = s0 + wid;
            int idx = (int)(res & 0xffffffffull);
            if (lane < 16) {
                ni_i[s * 16 + lane] = idx;
                out_ni[s * 16 + lane] = (float)idx;
            }
            // neighbor distances 1..3 are exactly the sort keys' top words
            if (lane >= 1 && lane < 4)
                intra_after[s * 6 + (lane - 1)] =
                    __uint_as_float((u32)(res >> 32));
            int i1 = __shfl(idx, 1, 64);
            int i2 = __shfl(idx, 2, 64);
            int i3 = __shfl(idx, 3, 64);
            if (lane < 3) {  // pairs (1,2),(1,3),(2,3)
                int pa = (lane == 2) ? i2 : i1;
                int pb = (lane == 0) ? i2 : i3;
                intra_after[s * 6 + 3 + lane] = pair_dist_f(ca[pa], ca[pb]);
            }
        }
    } else {
        int s0 = (bid - S_PTS / 4) * 2;
        float4 qs[2];
        qs[0] = cb[sidx[s0]];
        qs[1] = cb[sidx[s0 + 1]];
        u64 res = knn_selectq<32, 4, 8192, 2>(qs, cb, t, mins, buf, shm);
        if (wid < 2) {
            int s = s0 + wid;
            int idx = (int)(res & 0xffffffffull);
            if (lane < 4) a_before[s * 4 + lane] = idx;
            if (lane >= 1 && lane < 4)
                intra_before[s * 6 + (lane - 1)] =
                    __uint_as_float((u32)(res >> 32));
            int i1 = __shfl(idx, 1, 64);
            int i2 = __shfl(idx, 2, 64);
            int i3 = __shfl(idx, 3, 64);
            if (lane < 3) {
                int pa = (lane == 2) ? i2 : i1;
                int pb = (lane == 0) ? i2 : i3;
                intra_before[s * 6 + 3 + lane] = pair_dist_f(cb[pa], cb[pb]);
            }
        }
    }
}

// ---------------------------------------------------------------- rf_after assembly + adf
// 4 samples per block, one wave each. All distances fp32-gram (reference-exact).
__global__ __launch_bounds__(256) void assemble_kernel(
        const float4* __restrict__ ca, const float4* __restrict__ cb,
        const int* __restrict__ ni_i, const float* __restrict__ intra_after,
        const int* __restrict__ a_before, const float* __restrict__ intra_before,
        const int* __restrict__ sidx,
        float* __restrict__ out_rf, float* __restrict__ adf) {
    __shared__ int s_ni[4][16];
    __shared__ float s_rf[4][16 * 28];
    __shared__ float s_ia[4][8];
    int t = threadIdx.x, wid = t >> 6, lane = t & 63;
    int s = blockIdx.x * 4 + wid;
    if (lane < 16) s_ni[wid][lane] = ni_i[s * 16 + lane];
    if (lane < 6) s_ia[wid][lane] = intra_after[s * 6 + lane];
    __syncthreads();

    // inter block of rf: rf[s,k,12+p*4+q] = D_after(ni[s,p], ni[ni[s,k],q])
    int k = lane >> 2, qq = lane & 3;
    int nai_q = ni_i[s_ni[wid][k] * 16 + qq];
    float4 pq = ca[nai_q];
#pragma unroll
    for (int p = 0; p < 4; ++p) {
        float4 pp = ca[s_ni[wid][p]];
        s_rf[wid][k * 28 + 12 + p * 4 + qq] = pair_dist_f(pp, pq);
    }
    // center intra (ch 0..5) + neighbor intra (ch 6..11)
    for (int idx = lane; idx < 16 * 12; idx += 64) {
        int kk = idx / 12, c = idx % 12;
        float v = (c < 6) ? s_ia[wid][c] : intra_after[s_ni[wid][kk] * 6 + (c - 6)];
        s_rf[wid][kk * 28 + c] = v;
    }
    // adf: [intra_before(6), intra_after(6), inter(16)]
    if (lane < 16) {
        int p = lane >> 2, q2 = lane & 3;
        int ib = a_before[s * 4 + p];
        int ia = sidx[s_ni[wid][q2]];
        adf[s * 28 + 12 + lane] = pair_dist_f(cb[ib], cb[ia]);
    } else if (lane >= 32 && lane < 38) {
        adf[s * 28 + (lane - 32)] = intra_before[s * 6 + (lane - 32)];
    } else if (lane >= 40 && lane < 46) {
        adf[s * 28 + 6 + (lane - 40)] = s_ia[wid][lane - 40];
    }
    __syncthreads();
    const int base = s * 16 * 28;
    for (int idx = lane; idx < 16 * 28; idx += 64) out_rf[base + idx] = s_rf[wid][idx];
}

// ---------------------------------------------------------------- mlp1: y_wb[c][s] = adf@[Ww|Wb] + [bw|bb]
// 32 samples per block, 16 output channels per thread, 128 blocks.
// Also emits deterministic per-block channel partial sums for the BN stats.
__global__ __launch_bounds__(256) void mlp1_kernel(
        const float* __restrict__ adf,
        const float* __restrict__ Ww, const float* __restrict__ bw,
        const float* __restrict__ Wb, const float* __restrict__ bb,
        float* __restrict__ y_wb,
        float* __restrict__ part1, float* __restrict__ part2) {
    __shared__ float sW[28 * 128];   // col c<64: Ww, else Wb
    __shared__ float sb[128];
    __shared__ float sA[32 * 28];
    __shared__ float red[32][128];
    int t = threadIdx.x;
    for (int i = t; i < 28 * 128; i += 256) {
        int k = i >> 7, c = i & 127;
        sW[i] = (c < 64) ? Ww[k * 64 + c] : Wb[k * 64 + (c - 64)];
    }
    if (t < 128) sb[t] = (t < 64) ? bw[t] : bb[t - 64];
    int s0 = blockIdx.x * 32;
    for (int i = t; i < 32 * 28; i += 256) sA[i] = adf[s0 * 28 + i];
    __syncthreads();
    int sl = t >> 3, grp = t & 7;
    int s = s0 + sl;
    float acc[16];
#pragma unroll
    for (int k = 0; k < 16; ++k) acc[k] = sb[grp * 16 + k];
    for (int k2 = 0; k2 < 28; ++k2) {
        float a = sA[sl * 28 + k2];
#pragma unroll
        for (int k = 0; k < 16; ++k)
            acc[k] = fmaf(a, sW[k2 * 128 + grp * 16 + k], acc[k]);
    }
#pragma unroll
    for (int k = 0; k < 16; ++k) {
        y_wb[(grp * 16 + k) * 4096 + s] = acc[k];
        red[sl][grp * 16 + k] = acc[k];
    }
    __syncthreads();
    if (t < 128) {
        float s1 = 0.0f, s2 = 0.0f;
#pragma unroll 8
        for (int r = 0; r < 32; ++r) {
            float v = red[r][t];
            s1 += v;
            s2 = fmaf(v, v, s2);
        }
        part1[blockIdx.x * 128 + t] = s1;
        part2[blockIdx.x * 128 + t] = s2;
    }
}

// ---------------------------------------------------------------- mlp2: BN-scale prologue
// (from mlp1 partials); f1 = lrelu(feat*w + b); y_o = [f1,adf]@Wo + bo.
// Emits per-block channel partial sums of y_o (register-resident acc)
// for the output BN — same validated pattern as mlp1's partials.
__global__ __launch_bounds__(256) void mlp2_kernel(
        const float* __restrict__ y_wb,
        const float* __restrict__ part1, const float* __restrict__ part2,
        const float* __restrict__ gw, const float* __restrict__ betaw,
        const float* __restrict__ gb, const float* __restrict__ betab,
        const float* __restrict__ feature, const int* __restrict__ sidx,
        const float* __restrict__ adf,
        const float* __restrict__ Wo, const float* __restrict__ bo,
        float* __restrict__ y_o,
        float* __restrict__ part1o, float* __restrict__ part2o) {
    __shared__ float sW[92 * 128];       // 47104 B
    __shared__ float t2[16 * 129];       // padded staging; reused as `red` later
    __shared__ float scat[16 * 92];      // cat rows
    __shared__ float s_sc[128], s_sh[128];
    int t = threadIdx.x;
    int s0 = blockIdx.x * 16;
    if (t < 128) {
        float s1 = 0.0f, s2 = 0.0f;
        for (int b = 0; b < 128; ++b) {
            s1 += part1[b * 128 + t];
            s2 += part2[b * 128 + t];
        }
        float mean = s1 * (1.0f / 4096.0f);
        float var = s2 * (1.0f / 4096.0f) - mean * mean;
        float g = (t < 64) ? gw[t] : gb[t - 64];
        float be = (t < 64) ? betaw[t] : betab[t - 64];
        float sc = g / sqrtf(var + 1e-5f);
        s_sc[t] = sc;
        s_sh[t] = be - mean * sc;
    }
    for (int i = t; i < 92 * 128; i += 256) sW[i] = Wo[i];
    __syncthreads();
    for (int i = t; i < 16 * 128; i += 256) {
        int row = i & 15, c = i >> 4;
        t2[row * 129 + c] = fmaf(y_wb[c * 4096 + s0 + row], s_sc[c], s_sh[c]);
    }
    __syncthreads();
    for (int rr = 0; rr < 16; rr += 4) {
        int r = rr + (t >> 6);
        int c = t & 63;
        int si = sidx[s0 + r];
        float f = feature[si * 64 + c];
        float v = fmaf(f, t2[r * 129 + c], t2[r * 129 + 64 + c]);
        scat[r * 92 + c] = v >= 0.0f ? v : 0.2f * v;
    }
    for (int i = t; i < 16 * 28; i += 256) {
        int row = i / 28, k = i % 28;
        scat[row * 92 + 64 + k] = adf[(s0 + row) * 28 + k];
    }
    __syncthreads();   // after this barrier t2 is dead -> reuse as red
    int r = t >> 4, cg = t & 15;
    float acc[8];
#pragma unroll
    for (int j = 0; j < 8; ++j) acc[j] = bo[cg * 8 + j];
    for (int c = 0; c < 92; ++c) {
        float a = scat[r * 92 + c];
#pragma unroll
        for (int j = 0; j < 8; ++j)
            acc[j] = fmaf(a, sW[c * 128 + cg * 8 + j], acc[j]);
    }
    int s = s0 + r;
#pragma unroll
    for (int j = 0; j < 8; ++j) y_o[(cg * 8 + j) * 4096 + s] = acc[j];
    // per-block BN partials for the output stage (overlay on t2, stride 129)
    float* red = t2;
#pragma unroll
    for (int j = 0; j < 8; ++j) red[r * 129 + cg * 8 + j] = acc[j];
    __syncthreads();
    if (t < 128) {
        float s1 = 0.0f, s2 = 0.0f;
#pragma unroll 4
        for (int r2 = 0; r2 < 16; ++r2) {
            float v = red[r2 * 129 + t];
            s1 += v;
            s2 = fmaf(v, v, s2);
        }
        part1o[blockIdx.x * 128 + t] = s1;
        part2o[blockIdx.x * 128 + t] = s2;
    }
}

// ---------------------------------------------------------------- final:
// block per output channel; stats from mlp2 partials (no y_o stats pass),
// then single read-normalize-lrelu-write pass.
__global__ __launch_bounds__(256) void stats_final_kernel(
        const float* __restrict__ y_o,  // [128][4096]
        const float* __restrict__ part1o, const float* __restrict__ part2o,
        const float* __restrict__ go, const float* __restrict__ betao,
        float* __restrict__ out_feat) {
    int c = blockIdx.x;
    const float* p = y_o + c * 4096;
    __shared__ float l1[256], l2[256];
    __shared__ float s_sc, s_sh;
    // prologue: sum the 256 per-block partials for this channel
    l1[threadIdx.x] = part1o[threadIdx.x * 128 + c];
    l2[threadIdx.x] = part2o[threadIdx.x * 128 + c];
    __syncthreads();
    for (int off = 128; off; off >>= 1) {
        if (threadIdx.x < off) {
            l1[threadIdx.x] += l1[threadIdx.x + off];
            l2[threadIdx.x] += l2[threadIdx.x + off];
        }
        __syncthreads();
    }
    if (threadIdx.x == 0) {
        float mean = l1[0] * (1.0f / 4096.0f);
        float var = l2[0] * (1.0f / 4096.0f) - mean * mean;
        float sc = go[c] / sqrtf(var + 1e-5f);
        s_sc = sc;
        s_sh = betao[c] - mean * sc;
    }
    __syncthreads();
    float sc = s_sc, sh = s_sh;
    for (int i = threadIdx.x; i < 4096; i += 256) {
        float v = fmaf(p[i], sc, sh);
        v = v >= 0.0f ? v : 0.2f * v;
        out_feat[i * 128 + c] = v;
    }
}

// ----------------------------------------------------------------
extern "C" void kernel_launch(void* const* d_in, const int* in_sizes, int n_in,
                              void* d_out, int out_size, void* d_ws, size_t ws_size,
                              hipStream_t stream) {
    const float* xyz = (const float*)d_in[0];
    const float* feature = (const float*)d_in[1];
    const int* sidx = (const int*)d_in[2];
    const float* Ww = (const float*)d_in[3];
    const float* bw = (const float*)d_in[4];
    const float* gw = (const float*)d_in[5];
    const float* betaw = (const float*)d_in[6];
    const float* Wb = (const float*)d_in[7];
    const float* bb = (const float*)d_in[8];
    const float* gb = (const float*)d_in[9];
    const float* betab = (const float*)d_in[10];
    const float* Wo = (const float*)d_in[11];
    const float* bo = (const float*)d_in[12];
    const float* go = (const float*)d_in[13];
    const float* betao = (const float*)d_in[14];

    float* out = (float*)d_out;
    float* out_xyz = out;                                  // 4096*3
    float* out_feat = out + 12288;                         // 4096*128
    float* out_rf = out + 12288 + 524288;                  // 4096*16*28
    float* out_ni = out + 12288 + 524288 + 1835008;        // 4096*16

    float* ws = (float*)d_ws;
    float4* cb = (float4*)ws;                  // 8192 float4
    float4* ca = (float4*)(ws + 32768);        // 4096 float4
    int* a_before = (int*)(ws + 49152);        // 4096*4
    float* intra_before = ws + 65536;          // 4096*6
    int* ni_i = (int*)(ws + 90112);            // 4096*16
    float* intra_after = ws + 155648;          // 4096*6
    float* adf = ws + 180224;                  // 4096*28
    float* y_wb = ws + 294912;                 // 128*4096 (y_w then y_b)
    float* y_o = ws + 819200;                  // 128*4096
    float* part1 = ws + 1343488;               // 128 blocks * 128 ch
    float* part2 = ws + 1359872;               // 128 blocks * 128 ch
    float* part1o = ws + 1376256;              // 256 blocks * 128 ch
    float* part2o = ws + 1409024;              // 256 blocks * 128 ch

    stage_kernel<<<32, 256, 0, stream>>>(xyz, sidx, cb, ca, out_xyz);
    knn_kernel<<<S_PTS / 4 + S_PTS / 2, 256, 0, stream>>>(
        cb, ca, sidx, a_before, intra_before, ni_i, intra_after, out_ni);
    assemble_kernel<<<1024, 256, 0, stream>>>(ca, cb, ni_i, intra_after, a_before,
                                              intra_before, sidx, out_rf, adf);
    mlp1_kernel<<<128, 256, 0, stream>>>(adf, Ww, bw, Wb, bb, y_wb, part1, part2);
    mlp2_kernel<<<256, 256, 0, stream>>>(y_wb, part1, part2, gw, betaw, gb, betab,
                                         feature, sidx, adf, Wo, bo, y_o,
                                         part1o, part2o);
    stats_final_kernel<<<128, 256, 0, stream>>>(y_o, part1o, part2o, go, betao,
                                                out_feat);
}

// Round 11
// 158.624 us; speedup vs baseline: 1.3814x; 1.3814x over previous
//
#include <hip/hip_runtime.h>
#include <hip/hip_bf16.h>
#include <math.h>

#define N_PTS 8192
#define S_PTS 4096
typedef unsigned long long u64;
typedef unsigned u32;

// Strict fp32 gram-formula d^2 (bit-identical to the reference cdist pipeline).
__device__ __forceinline__ float d2_f32_gram(const float4 a, const float4 b) {
    float dot = __fadd_rn(__fadd_rn(__fmul_rn(a.x, b.x), __fmul_rn(a.y, b.y)),
                          __fmul_rn(a.z, b.z));
    float d2 = __fsub_rn(__fadd_rn(a.w, b.w), __fmul_rn(2.0f, dot));
    return fmaxf(d2, 0.0f);
}

// Reference-exact pair distance: fp32 gram + fp32 sqrt (== cdist output bits).
__device__ __forceinline__ float pair_dist_f(const float4 a, const float4 b) {
    float d2 = d2_f32_gram(a, b);
    return d2 > 0.0f ? __fsqrt_rn(d2) : 0.0f;
}

// ---------------------------------------------------------------- stage
__global__ __launch_bounds__(256) void stage_kernel(
        const float* __restrict__ xyz, const int* __restrict__ sidx,
        float4* __restrict__ cb, float4* __restrict__ ca,
        float* __restrict__ out_xyz_s) {
    int i = blockIdx.x * blockDim.x + threadIdx.x;
    if (i < N_PTS) {
        float x = xyz[i * 3 + 0], y = xyz[i * 3 + 1], z = xyz[i * 3 + 2];
        float sq = __fadd_rn(__fadd_rn(__fmul_rn(x, x), __fmul_rn(y, y)),
                             __fmul_rn(z, z));
        cb[i] = make_float4(x, y, z, sq);
    }
    if (i < S_PTS) {
        int si = sidx[i];
        float x = xyz[si * 3 + 0], y = xyz[si * 3 + 1], z = xyz[si * 3 + 2];
        float sq = __fadd_rn(__fadd_rn(__fmul_rn(x, x), __fmul_rn(y, y)),
                             __fmul_rn(z, z));
        ca[i] = make_float4(x, y, z, sq);
        out_xyz_s[i * 3 + 0] = x;
        out_xyz_s[i * 3 + 1] = y;
        out_xyz_s[i * 3 + 2] = z;
    }
}

// ---------------------------------------------------------------- knn select
// Validated r1/r4/r6/r9 structure: Q queries per block share each candidate
// load; wave w owns query w for tau-sort / final-sort / epilogue.
// NOTE (r10 lesson): __launch_bounds__(256,4) with 64 VGPR is the max-occupancy
// allocation — the wave64 VGPR pool is 256/SIMD, so (256,8) caps VGPR at 32 and
// spills d2b (191 MB scratch traffic, +60 µs). Do not raise the bound.

// full single-wave ladder (ultra-rare fallback), per owning wave
template <int KOUT, int ITERS>
__device__ u64 knn_full_ladder(const float4 q, const float4* __restrict__ cand,
                               int lane) {
    u32 Lk[KOUT], Li[KOUT];
#pragma unroll
    for (int j = 0; j < KOUT; ++j) { Lk[j] = 0xFFFFFFFFu; Li[j] = 0xFFFFFFFFu; }
    int c = lane;
    for (int tt = 0; tt < ITERS; ++tt, c += 64) {
        float d2 = d2_f32_gram(q, cand[c]);
        float Df = d2 > 0.0f ? __fsqrt_rn(d2) : 0.0f;
        u32 kb = __float_as_uint(Df);
        if (kb < Lk[KOUT - 1]) {
#pragma unroll
            for (int j = KOUT - 1; j >= 1; --j) {
                bool up = kb < Lk[j - 1], ins = kb < Lk[j];
                Lk[j] = up ? Lk[j - 1] : (ins ? kb : Lk[j]);
                Li[j] = up ? Li[j - 1] : (ins ? (u32)c : Li[j]);
            }
            bool i0 = kb < Lk[0];
            Lk[0] = i0 ? kb : Lk[0];
            Li[0] = i0 ? (u32)c : Li[0];
        }
    }
    u64 Lu[KOUT];
#pragma unroll
    for (int j = 0; j < KOUT; ++j) Lu[j] = ((u64)Lk[j] << 32) | (u64)Li[j];
    u64 res = ~0ull;
#pragma unroll
    for (int r = 0; r < KOUT; ++r) {
        u64 m = Lu[0];
#pragma unroll
        for (int off = 32; off >= 1; off >>= 1) {
            u64 o = __shfl_xor(m, off, 64);
            m = (o < m) ? o : m;
        }
        if (lane == r) res = m;
        if (Lu[0] == m) {
#pragma unroll
            for (int j = 0; j < KOUT - 1; ++j) Lu[j] = Lu[j + 1];
            Lu[KOUT - 1] = ~0ull;
        }
    }
    return res;
}

// Sort the compacted candidate buffer of one query (executed by its owning
// wave only).
template <int K, int NC>
__device__ u64 final_select(const float4 qq, const float4* __restrict__ cand,
                            const u64* bufq, u32 cnt, int lane) {
    if (cnt <= 64u) {
        u64 v = (lane < (int)cnt) ? bufq[lane] : ~0ull;
#pragma unroll
        for (int k = 2; k <= 64; k <<= 1) {
#pragma unroll
            for (int j2 = k >> 1; j2 >= 1; j2 >>= 1) {
                u64 o = __shfl_xor(v, j2, 64);
                bool keepMin = (((lane & j2) == 0) == ((lane & k) == 0));
                bool less = o < v;
                v = keepMin ? (less ? o : v) : (less ? v : o);
            }
        }
        return v;  // lane r holds rank r
    } else if (cnt <= 256u) {
        // per-lane sorted-4 (<=4 cands/lane) + K-round extract
        u64 L0 = ~0ull, L1 = ~0ull, L2 = ~0ull, L3 = ~0ull;
        for (u32 mm = lane; mm < cnt; mm += 64) {
            u64 kk = bufq[mm];
            if (kk < L3) {
                if (kk < L1) {
                    L3 = L2; L2 = L1;
                    if (kk < L0) { L1 = L0; L0 = kk; } else L1 = kk;
                } else {
                    if (kk < L2) { L3 = L2; L2 = kk; } else L3 = kk;
                }
            }
        }
        u64 res = ~0ull;
#pragma unroll
        for (int r = 0; r < K; ++r) {
            u64 mr = L0;
#pragma unroll
            for (int off = 32; off >= 1; off >>= 1) {
                u64 o = __shfl_xor(mr, off, 64);
                mr = (o < mr) ? o : mr;
            }
            if (lane == r) res = mr;
            if (L0 == mr) { L0 = L1; L1 = L2; L2 = L3; L3 = ~0ull; }
        }
        return res;
    }
    return knn_full_ladder<K, NC / 64>(qq, cand, lane);
}

// Q-query batched select. mins: Q*256 u32, buf: Q*256 u64, shm: >= Q + 4*Q u32.
// Returns the (D,idx) record for rank `lane` of query `wid` (valid iff wid<Q).
template <int J, int K, int NC, int Q>
__device__ __forceinline__ u64 knn_selectq(
        const float4* qs, const float4* __restrict__ cand, int t,
        u32* mins, u64* buf, u32* shm) {
    int lane = t & 63, wid = t >> 6;
    // pass 1: d^2 bits in registers + per-thread min, Q queries per load
    u32 d2b[Q][J];
    u32 m[Q];
#pragma unroll
    for (int qi = 0; qi < Q; ++qi) m[qi] = 0xFFFFFFFFu;
#pragma unroll
    for (int j = 0; j < J; ++j) {
        float4 c = cand[t + 256 * j];
#pragma unroll
        for (int qi = 0; qi < Q; ++qi) {
            u32 b = __float_as_uint(d2_f32_gram(qs[qi], c));
            d2b[qi][j] = b;
            m[qi] = b < m[qi] ? b : m[qi];
        }
    }
#pragma unroll
    for (int qi = 0; qi < Q; ++qi) mins[qi * 256 + t] = m[qi];
    __syncthreads();
    // tau[qi] = K-th smallest of 64 column-minima (wave qi, bitonic sort64 u32)
    if (wid < Q) {
        const u32* mq = mins + wid * 256;
        u32 v = mq[lane];
        u32 v2 = mq[lane + 64];  v = v2 < v ? v2 : v;
        v2 = mq[lane + 128];     v = v2 < v ? v2 : v;
        v2 = mq[lane + 192];     v = v2 < v ? v2 : v;
#pragma unroll
        for (int k = 2; k <= 64; k <<= 1) {
#pragma unroll
            for (int j2 = k >> 1; j2 >= 1; j2 >>= 1) {
                u32 o = __shfl_xor(v, j2, 64);
                bool keepMin = (((lane & j2) == 0) == ((lane & k) == 0));
                bool less = o < v;
                v = keepMin ? (less ? o : v) : (less ? v : o);
            }
        }
        if (lane == K - 1) shm[wid] = v;
    }
    __syncthreads();
    // pass 2: count qualifying + block prefix scan, per query
    u32 tau[Q], c[Q], x[Q];
#pragma unroll
    for (int qi = 0; qi < Q; ++qi) {
        tau[qi] = shm[qi];
        u32 cc = 0;
#pragma unroll
        for (int j = 0; j < J; ++j) cc += (d2b[qi][j] <= tau[qi]) ? 1u : 0u;
        c[qi] = cc;
        u32 xx = cc;
#pragma unroll
        for (int off = 1; off < 64; off <<= 1) {
            u32 y = __shfl_up(xx, off, 64);
            if (lane >= off) xx += y;
        }
        x[qi] = xx;
        if (lane == 63) shm[Q + qi * 4 + wid] = xx;
    }
    __syncthreads();
    u32 cnt[Q];
#pragma unroll
    for (int qi = 0; qi < Q; ++qi) {
        u32 base = x[qi] - c[qi];
        for (int w = 0; w < wid; ++w) base += shm[Q + qi * 4 + w];
        cnt[qi] = shm[Q + qi * 4 + 0] + shm[Q + qi * 4 + 1] +
                  shm[Q + qi * 4 + 2] + shm[Q + qi * 4 + 3];
        if (cnt[qi] <= 256u) {
            u32 off = base;
#pragma unroll
            for (int j = 0; j < J; ++j) {
                if (d2b[qi][j] <= tau[qi]) {
                    float d2 = __uint_as_float(d2b[qi][j]);
                    float D = d2 > 0.0f ? __fsqrt_rn(d2) : 0.0f;
                    buf[qi * 256 + off++] = ((u64)__float_as_uint(D) << 32) |
                                            (u64)(u32)(t + 256 * j);
                }
            }
        }
    }
    __syncthreads();
    u64 res = ~0ull;
#pragma unroll
    for (int qi = 0; qi < Q; ++qi)
        if (wid == qi)
            res = final_select<K, NC>(qs[qi], cand, buf + qi * 256, cnt[qi], lane);
    return res;
}

// blocks [0, 1024): "after" (top-16 over ca, 4 queries/block);
// blocks [1024, 3072): "before" (top-4 over cb, 2 queries/block)
__global__ __launch_bounds__(256, 4) void knn_kernel(
        const float4* __restrict__ cb, const float4* __restrict__ ca,
        const int* __restrict__ sidx,
        int* __restrict__ a_before, float* __restrict__ intra_before,
        int* __restrict__ ni_i, float* __restrict__ intra_after,
        float* __restrict__ out_ni) {
    __shared__ u32 mins[4 * 256];
    __shared__ u64 buf[4 * 256];
    __shared__ u32 shm[24];
    int t = threadIdx.x, lane = t & 63, wid = t >> 6;
    int bid = blockIdx.x;
    if (bid < S_PTS / 4) {
        int s0 = bid * 4;
        float4 qs[4];
#pragma unroll
        for (int qi = 0; qi < 4; ++qi) qs[qi] = ca[s0 + qi];
        u64 res = knn_selectq<16, 16, 4096, 4>(qs, ca, t, mins, buf, shm);
        if (wid < 4) {
            int s = s0 + wid;
            int idx = (int)(res & 0xffffffffull);
            if (lane < 16) {
                ni_i[s * 16 + lane] = idx;
                out_ni[s * 16 + lane] = (float)idx;
            }
            // neighbor distances 1..3 are exactly the sort keys' top words
            if (lane >= 1 && lane < 4)
                intra_after[s * 6 + (lane - 1)] =
                    __uint_as_float((u32)(res >> 32));
            int i1 = __shfl(idx, 1, 64);
            int i2 = __shfl(idx, 2, 64);
            int i3 = __shfl(idx, 3, 64);
            if (lane < 3) {  // pairs (1,2),(1,3),(2,3)
                int pa = (lane == 2) ? i2 : i1;
                int pb = (lane == 0) ? i2 : i3;
                intra_after[s * 6 + 3 + lane] = pair_dist_f(ca[pa], ca[pb]);
            }
        }
    } else {
        int s0 = (bid - S_PTS / 4) * 2;
        float4 qs[2];
        qs[0] = cb[sidx[s0]];
        qs[1] = cb[sidx[s0 + 1]];
        u64 res = knn_selectq<32, 4, 8192, 2>(qs, cb, t, mins, buf, shm);
        if (wid < 2) {
            int s = s0 + wid;
            int idx = (int)(res & 0xffffffffull);
            if (lane < 4) a_before[s * 4 + lane] = idx;
            if (lane >= 1 && lane < 4)
                intra_before[s * 6 + (lane - 1)] =
                    __uint_as_float((u32)(res >> 32));
            int i1 = __shfl(idx, 1, 64);
            int i2 = __shfl(idx, 2, 64);
            int i3 = __shfl(idx, 3, 64);
            if (lane < 3) {
                int pa = (lane == 2) ? i2 : i1;
                int pb = (lane == 0) ? i2 : i3;
                intra_before[s * 6 + 3 + lane] = pair_dist_f(cb[pa], cb[pb]);
            }
        }
    }
}

// ---------------------------------------------------------------- rf_after assembly + adf
// 4 samples per block, one wave each. All distances fp32-gram (reference-exact).
__global__ __launch_bounds__(256) void assemble_kernel(
        const float4* __restrict__ ca, const float4* __restrict__ cb,
        const int* __restrict__ ni_i, const float* __restrict__ intra_after,
        const int* __restrict__ a_before, const float* __restrict__ intra_before,
        const int* __restrict__ sidx,
        float* __restrict__ out_rf, float* __restrict__ adf) {
    __shared__ int s_ni[4][16];
    __shared__ float s_rf[4][16 * 28];
    __shared__ float s_ia[4][8];
    int t = threadIdx.x, wid = t >> 6, lane = t & 63;
    int s = blockIdx.x * 4 + wid;
    if (lane < 16) s_ni[wid][lane] = ni_i[s * 16 + lane];
    if (lane < 6) s_ia[wid][lane] = intra_after[s * 6 + lane];
    __syncthreads();

    // inter block of rf: rf[s,k,12+p*4+q] = D_after(ni[s,p], ni[ni[s,k],q])
    int k = lane >> 2, qq = lane & 3;
    int nai_q = ni_i[s_ni[wid][k] * 16 + qq];
    float4 pq = ca[nai_q];
#pragma unroll
    for (int p = 0; p < 4; ++p) {
        float4 pp = ca[s_ni[wid][p]];
        s_rf[wid][k * 28 + 12 + p * 4 + qq] = pair_dist_f(pp, pq);
    }
    // center intra (ch 0..5) + neighbor intra (ch 6..11)
    for (int idx = lane; idx < 16 * 12; idx += 64) {
        int kk = idx / 12, c = idx % 12;
        float v = (c < 6) ? s_ia[wid][c] : intra_after[s_ni[wid][kk] * 6 + (c - 6)];
        s_rf[wid][kk * 28 + c] = v;
    }
    // adf: [intra_before(6), intra_after(6), inter(16)]
    if (lane < 16) {
        int p = lane >> 2, q2 = lane & 3;
        int ib = a_before[s * 4 + p];
        int ia = sidx[s_ni[wid][q2]];
        adf[s * 28 + 12 + lane] = pair_dist_f(cb[ib], cb[ia]);
    } else if (lane >= 32 && lane < 38) {
        adf[s * 28 + (lane - 32)] = intra_before[s * 6 + (lane - 32)];
    } else if (lane >= 40 && lane < 46) {
        adf[s * 28 + 6 + (lane - 40)] = s_ia[wid][lane - 40];
    }
    __syncthreads();
    const int base = s * 16 * 28;
    for (int idx = lane; idx < 16 * 28; idx += 64) out_rf[base + idx] = s_rf[wid][idx];
}

// ---------------------------------------------------------------- mlp1: y_wb[c][s] = adf@[Ww|Wb] + [bw|bb]
// 32 samples per block, 16 output channels per thread, 128 blocks.
// Also emits deterministic per-block channel partial sums for the BN stats.
__global__ __launch_bounds__(256) void mlp1_kernel(
        const float* __restrict__ adf,
        const float* __restrict__ Ww, const float* __restrict__ bw,
        const float* __restrict__ Wb, const float* __restrict__ bb,
        float* __restrict__ y_wb,
        float* __restrict__ part1, float* __restrict__ part2) {
    __shared__ float sW[28 * 128];   // col c<64: Ww, else Wb
    __shared__ float sb[128];
    __shared__ float sA[32 * 28];
    __shared__ float red[32][128];
    int t = threadIdx.x;
    for (int i = t; i < 28 * 128; i += 256) {
        int k = i >> 7, c = i & 127;
        sW[i] = (c < 64) ? Ww[k * 64 + c] : Wb[k * 64 + (c - 64)];
    }
    if (t < 128) sb[t] = (t < 64) ? bw[t] : bb[t - 64];
    int s0 = blockIdx.x * 32;
    for (int i = t; i < 32 * 28; i += 256) sA[i] = adf[s0 * 28 + i];
    __syncthreads();
    int sl = t >> 3, grp = t & 7;
    int s = s0 + sl;
    float acc[16];
#pragma unroll
    for (int k = 0; k < 16; ++k) acc[k] = sb[grp * 16 + k];
    for (int k2 = 0; k2 < 28; ++k2) {
        float a = sA[sl * 28 + k2];
#pragma unroll
        for (int k = 0; k < 16; ++k)
            acc[k] = fmaf(a, sW[k2 * 128 + grp * 16 + k], acc[k]);
    }
#pragma unroll
    for (int k = 0; k < 16; ++k) {
        y_wb[(grp * 16 + k) * 4096 + s] = acc[k];
        red[sl][grp * 16 + k] = acc[k];
    }
    __syncthreads();
    if (t < 128) {
        float s1 = 0.0f, s2 = 0.0f;
#pragma unroll 8
        for (int r = 0; r < 32; ++r) {
            float v = red[r][t];
            s1 += v;
            s2 = fmaf(v, v, s2);
        }
        part1[blockIdx.x * 128 + t] = s1;
        part2[blockIdx.x * 128 + t] = s2;
    }
}

// ---------------------------------------------------------------- mlp2: BN-scale prologue
// (from mlp1 partials); f1 = lrelu(feat*w + b); y_o = [f1,adf]@Wo + bo.
// Emits per-block channel partial sums of y_o (register-resident acc)
// for the output BN — same validated pattern as mlp1's partials.
__global__ __launch_bounds__(256) void mlp2_kernel(
        const float* __restrict__ y_wb,
        const float* __restrict__ part1, const float* __restrict__ part2,
        const float* __restrict__ gw, const float* __restrict__ betaw,
        const float* __restrict__ gb, const float* __restrict__ betab,
        const float* __restrict__ feature, const int* __restrict__ sidx,
        const float* __restrict__ adf,
        const float* __restrict__ Wo, const float* __restrict__ bo,
        float* __restrict__ y_o,
        float* __restrict__ part1o, float* __restrict__ part2o) {
    __shared__ float sW[92 * 128];       // 47104 B
    __shared__ float t2[16 * 129];       // padded staging; reused as `red` later
    __shared__ float scat[16 * 92];      // cat rows
    __shared__ float s_sc[128], s_sh[128];
    int t = threadIdx.x;
    int s0 = blockIdx.x * 16;
    if (t < 128) {
        float s1 = 0.0f, s2 = 0.0f;
        for (int b = 0; b < 128; ++b) {
            s1 += part1[b * 128 + t];
            s2 += part2[b * 128 + t];
        }
        float mean = s1 * (1.0f / 4096.0f);
        float var = s2 * (1.0f / 4096.0f) - mean * mean;
        float g = (t < 64) ? gw[t] : gb[t - 64];
        float be = (t < 64) ? betaw[t] : betab[t - 64];
        float sc = g / sqrtf(var + 1e-5f);
        s_sc[t] = sc;
        s_sh[t] = be - mean * sc;
    }
    for (int i = t; i < 92 * 128; i += 256) sW[i] = Wo[i];
    __syncthreads();
    for (int i = t; i < 16 * 128; i += 256) {
        int row = i & 15, c = i >> 4;
        t2[row * 129 + c] = fmaf(y_wb[c * 4096 + s0 + row], s_sc[c], s_sh[c]);
    }
    __syncthreads();
    for (int rr = 0; rr < 16; rr += 4) {
        int r = rr + (t >> 6);
        int c = t & 63;
        int si = sidx[s0 + r];
        float f = feature[si * 64 + c];
        float v = fmaf(f, t2[r * 129 + c], t2[r * 129 + 64 + c]);
        scat[r * 92 + c] = v >= 0.0f ? v : 0.2f * v;
    }
    for (int i = t; i < 16 * 28; i += 256) {
        int row = i / 28, k = i % 28;
        scat[row * 92 + 64 + k] = adf[(s0 + row) * 28 + k];
    }
    __syncthreads();   // after this barrier t2 is dead -> reuse as red
    int r = t >> 4, cg = t & 15;
    float acc[8];
#pragma unroll
    for (int j = 0; j < 8; ++j) acc[j] = bo[cg * 8 + j];
    for (int c = 0; c < 92; ++c) {
        float a = scat[r * 92 + c];
#pragma unroll
        for (int j = 0; j < 8; ++j)
            acc[j] = fmaf(a, sW[c * 128 + cg * 8 + j], acc[j]);
    }
    int s = s0 + r;
#pragma unroll
    for (int j = 0; j < 8; ++j) y_o[(cg * 8 + j) * 4096 + s] = acc[j];
    // per-block BN partials for the output stage (overlay on t2, stride 129)
    float* red = t2;
#pragma unroll
    for (int j = 0; j < 8; ++j) red[r * 129 + cg * 8 + j] = acc[j];
    __syncthreads();
    if (t < 128) {
        float s1 = 0.0f, s2 = 0.0f;
#pragma unroll 4
        for (int r2 = 0; r2 < 16; ++r2) {
            float v = red[r2 * 129 + t];
            s1 += v;
            s2 = fmaf(v, v, s2);
        }
        part1o[blockIdx.x * 128 + t] = s1;
        part2o[blockIdx.x * 128 + t] = s2;
    }
}

// ---------------------------------------------------------------- final:
// block per output channel; stats from mlp2 partials (no y_o stats pass),
// then single read-normalize-lrelu-write pass.
__global__ __launch_bounds__(256) void stats_final_kernel(
        const float* __restrict__ y_o,  // [128][4096]
        const float* __restrict__ part1o, const float* __restrict__ part2o,
        const float* __restrict__ go, const float* __restrict__ betao,
        float* __restrict__ out_feat) {
    int c = blockIdx.x;
    const float* p = y_o + c * 4096;
    __shared__ float l1[256], l2[256];
    __shared__ float s_sc, s_sh;
    // prologue: sum the 256 per-block partials for this channel
    l1[threadIdx.x] = part1o[threadIdx.x * 128 + c];
    l2[threadIdx.x] = part2o[threadIdx.x * 128 + c];
    __syncthreads();
    for (int off = 128; off; off >>= 1) {
        if (threadIdx.x < off) {
            l1[threadIdx.x] += l1[threadIdx.x + off];
            l2[threadIdx.x] += l2[threadIdx.x + off];
        }
        __syncthreads();
    }
    if (threadIdx.x == 0) {
        float mean = l1[0] * (1.0f / 4096.0f);
        float var = l2[0] * (1.0f / 4096.0f) - mean * mean;
        float sc = go[c] / sqrtf(var + 1e-5f);
        s_sc = sc;
        s_sh = betao[c] - mean * sc;
    }
    __syncthreads();
    float sc = s_sc, sh = s_sh;
    for (int i = threadIdx.x; i < 4096; i += 256) {
        float v = fmaf(p[i], sc, sh);
        v = v >= 0.0f ? v : 0.2f * v;
        out_feat[i * 128 + c] = v;
    }
}

// ----------------------------------------------------------------
extern "C" void kernel_launch(void* const* d_in, const int* in_sizes, int n_in,
                              void* d_out, int out_size, void* d_ws, size_t ws_size,
                              hipStream_t stream) {
    const float* xyz = (const float*)d_in[0];
    const float* feature = (const float*)d_in[1];
    const int* sidx = (const int*)d_in[2];
    const float* Ww = (const float*)d_in[3];
    const float* bw = (const float*)d_in[4];
    const float* gw = (const float*)d_in[5];
    const float* betaw = (const float*)d_in[6];
    const float* Wb = (const float*)d_in[7];
    const float* bb = (const float*)d_in[8];
    const float* gb = (const float*)d_in[9];
    const float* betab = (const float*)d_in[10];
    const float* Wo = (const float*)d_in[11];
    const float* bo = (const float*)d_in[12];
    const float* go = (const float*)d_in[13];
    const float* betao = (const float*)d_in[14];

    float* out = (float*)d_out;
    float* out_xyz = out;                                  // 4096*3
    float* out_feat = out + 12288;                         // 4096*128
    float* out_rf = out + 12288 + 524288;                  // 4096*16*28
    float* out_ni = out + 12288 + 524288 + 1835008;        // 4096*16

    float* ws = (float*)d_ws;
    float4* cb = (float4*)ws;                  // 8192 float4
    float4* ca = (float4*)(ws + 32768);        // 4096 float4
    int* a_before = (int*)(ws + 49152);        // 4096*4
    float* intra_before = ws + 65536;          // 4096*6
    int* ni_i = (int*)(ws + 90112);            // 4096*16
    float* intra_after = ws + 155648;          // 4096*6
    float* adf = ws + 180224;                  // 4096*28
    float* y_wb = ws + 294912;                 // 128*4096 (y_w then y_b)
    float* y_o = ws + 819200;                  // 128*4096
    float* part1 = ws + 1343488;               // 128 blocks * 128 ch
    float* part2 = ws + 1359872;               // 128 blocks * 128 ch
    float* part1o = ws + 1376256;              // 256 blocks * 128 ch
    float* part2o = ws + 1409024;              // 256 blocks * 128 ch

    stage_kernel<<<32, 256, 0, stream>>>(xyz, sidx, cb, ca, out_xyz);
    knn_kernel<<<S_PTS / 4 + S_PTS / 2, 256, 0, stream>>>(
        cb, ca, sidx, a_before, intra_before, ni_i, intra_after, out_ni);
    assemble_kernel<<<1024, 256, 0, stream>>>(ca, cb, ni_i, intra_after, a_before,
                                              intra_before, sidx, out_rf, adf);
    mlp1_kernel<<<128, 256, 0, stream>>>(adf, Ww, bw, Wb, bb, y_wb, part1, part2);
    mlp2_kernel<<<256, 256, 0, stream>>>(y_wb, part1, part2, gw, betaw, gb, betab,
                                         feature, sidx, adf, Wo, bo, y_o,
                                         part1o, part2o);
    stats_final_kernel<<<128, 256, 0, stream>>>(y_o, part1o, part2o, go, betao,
                                                out_feat);
}